// Round 1
// baseline (600.484 us; speedup 1.0000x reference)
//
#include <hip/hip_runtime.h>
#include <hip/hip_bf16.h>

// Sizes fixed by the problem
#define TT 240
#define FEAT 180
#define HID 90

typedef __attribute__((ext_vector_type(8))) short bf16x8;
typedef __attribute__((ext_vector_type(4))) float f32x4;

static __device__ __forceinline__ float bf2f(short s) {
    unsigned int u = ((unsigned int)(unsigned short)s) << 16;
    union { unsigned int u; float f; } c; c.u = u; return c.f;
}
static __device__ __forceinline__ short f2bf(float f) {
    union { float f; unsigned int u; } c; c.f = f;
    unsigned int u = c.u;
    u += 0x7fffu + ((u >> 16) & 1u);   // RNE (inputs finite)
    return (short)(u >> 16);
}
static __device__ __forceinline__ float sigm(float x) {
    return 1.f / (1.f + __expf(-x));
}
static __device__ __forceinline__ float tanh_(float x) {
    float e = __expf(-2.f * fabsf(x));     // e in (0,1], no inf
    float r = (1.f - e) / (1.f + e);
    return (x >= 0.f) ? r : -r;
}

// ---------------------------------------------------------------------------
// Weight repack: drop f-gate; pad gates 90->96 rows, K 180->192 / 90->96.
// wencP: [288][192] bf16 (rows = gate*96+h, gates i,g,o)
// wdecP: [288][96]  bf16
// woutB: [40][21600] bf16
// ---------------------------------------------------------------------------
__global__ __launch_bounds__(256) void k_prep(
    const float* __restrict__ outW, const float* __restrict__ encW,
    const float* __restrict__ decW,
    short* __restrict__ woutB, short* __restrict__ wencP, short* __restrict__ wdecP)
{
    int idx = blockIdx.x * 256 + threadIdx.x;
    if (idx < 864000) { woutB[idx] = f2bf(outW[idx]); return; }
    idx -= 864000;
    if (idx < 288 * 192) {
        int row = idx / 192, k = idx - row * 192;
        int gi = row / 96, h = row - gi * 96;
        float v = 0.f;
        if (h < 90 && k < 180) {
            int srow = (gi == 0 ? 0 : (gi == 1 ? 180 : 270)) + h;
            v = encW[srow * 180 + k];
        }
        wencP[idx] = f2bf(v);
        return;
    }
    idx -= 288 * 192;
    if (idx < 288 * 96) {
        int row = idx / 96, k = idx - row * 96;
        int gi = row / 96, h = row - gi * 96;
        float v = 0.f;
        if (h < 90 && k < 90) {
            int srow = (gi == 0 ? 0 : (gi == 1 ? 180 : 270)) + h;
            v = decW[srow * 90 + k];
        }
        wdecP[idx] = f2bf(v);
    }
}

// ---------------------------------------------------------------------------
// Encoder: per block 64 rows (m = b*240+t) x all 90 h.
// 6 waves; wave wv owns h-tile [wv*16, wv*16+16) with W frags in registers.
// A tile gathered from x (fused transpose + fp32->bf16) into LDS.
// h1[m][96] bf16 (cols 90..95 = benign garbage, zeroed-out by W pad in dec).
// ---------------------------------------------------------------------------
__global__ __launch_bounds__(384) void k_enc(
    const float* __restrict__ x, const short* __restrict__ wencP,
    const float* __restrict__ b_ih, const float* __restrict__ b_hh,
    short* __restrict__ h1, int M)
{
    __shared__ short As[64][200];   // pad 192->200: stride 400B = 25*16 -> conflict-free
    const int tid  = threadIdx.x;
    const int lane = tid & 63;
    const int wv   = tid >> 6;      // 0..5 = h-tile
    const int m0   = blockIdx.x * 64;
    const int r15  = lane & 15;
    const int k8   = lane >> 4;

    // W fragments: 3 gates x 6 k-steps, held in VGPRs for the whole block
    bf16x8 wf[3][6];
    #pragma unroll
    for (int g = 0; g < 3; ++g) {
        int row = g * 96 + wv * 16 + r15;
        const short* wp = wencP + row * 192 + k8 * 8;
        #pragma unroll
        for (int kk = 0; kk < 6; ++kk)
            wf[g][kk] = *(const bf16x8*)(wp + kk * 32);
    }
    // biases (f-gate skipped); clamp for pad cols (values discarded)
    int h  = wv * 16 + r15;
    int hc = (h < 90) ? h : 89;
    float bI = b_ih[hc]       + b_hh[hc];
    float bG = b_ih[180 + hc] + b_hh[180 + hc];
    float bO = b_ih[270 + hc] + b_hh[270 + hc];

    // Stage A tile: row r holds xe[m0+r][k], k = f = c*60+ck; x[(b*180+f)*240+t]
    {
        int r = lane;
        int m = m0 + r;
        bool mv = (m < M);
        int b = m / 240;
        int t = m - b * 240;
        const float* xb = x + (b * 180) * 240 + t;
        #pragma unroll
        for (int i = 0; i < 4; ++i) {
            int g = wv + 6 * i;            // granule 0..23 (8 bf16 each)
            short tmp[8];
            #pragma unroll
            for (int j = 0; j < 8; ++j) {
                float v = mv ? xb[(g * 8 + j) * 240] : 0.f;
                tmp[j] = f2bf(v);
            }
            *(uint4*)(&As[r][g * 8]) = *(const uint4*)tmp;
        }
    }
    __syncthreads();

    const int rbase = (lane >> 4) * 4;
    #pragma unroll
    for (int rs = 0; rs < 4; ++rs) {
        f32x4 accI = {0.f, 0.f, 0.f, 0.f};
        f32x4 accG = {0.f, 0.f, 0.f, 0.f};
        f32x4 accO = {0.f, 0.f, 0.f, 0.f};
        #pragma unroll
        for (int kk = 0; kk < 6; ++kk) {
            bf16x8 a = *(const bf16x8*)(&As[rs * 16 + r15][kk * 32 + k8 * 8]);
            accI = __builtin_amdgcn_mfma_f32_16x16x32_bf16(a, wf[0][kk], accI, 0, 0, 0);
            accG = __builtin_amdgcn_mfma_f32_16x16x32_bf16(a, wf[1][kk], accG, 0, 0, 0);
            accO = __builtin_amdgcn_mfma_f32_16x16x32_bf16(a, wf[2][kk], accO, 0, 0, 0);
        }
        #pragma unroll
        for (int rg = 0; rg < 4; ++rg) {
            int m = m0 + rs * 16 + rbase + rg;
            float iv = accI[rg] + bI;
            float gv = accG[rg] + bG;
            float ov = accO[rg] + bO;
            float c  = sigm(iv) * tanh_(gv);
            float hv = sigm(ov) * tanh_(c);
            float o1 = sigm(hv);            // extra sigmoid on encoder output
            if (m < M) h1[m * 96 + h] = f2bf(o1);
        }
    }
}

// ---------------------------------------------------------------------------
// Decoder: same skeleton, K=96 (3 k-steps). h2 stored packed [B][21600].
// ---------------------------------------------------------------------------
__global__ __launch_bounds__(384) void k_dec(
    const short* __restrict__ h1, const short* __restrict__ wdecP,
    const float* __restrict__ b_ih, const float* __restrict__ b_hh,
    short* __restrict__ h2, int M)
{
    __shared__ short As[64][104];   // stride 208B = 13*16 -> conflict-free
    const int tid  = threadIdx.x;
    const int lane = tid & 63;
    const int wv   = tid >> 6;
    const int m0   = blockIdx.x * 64;
    const int r15  = lane & 15;
    const int k8   = lane >> 4;

    bf16x8 wf[3][3];
    #pragma unroll
    for (int g = 0; g < 3; ++g) {
        int row = g * 96 + wv * 16 + r15;
        const short* wp = wdecP + row * 96 + k8 * 8;
        #pragma unroll
        for (int kk = 0; kk < 3; ++kk)
            wf[g][kk] = *(const bf16x8*)(wp + kk * 32);
    }
    int h  = wv * 16 + r15;
    int hc = (h < 90) ? h : 89;
    float bI = b_ih[hc]       + b_hh[hc];
    float bG = b_ih[180 + hc] + b_hh[180 + hc];
    float bO = b_ih[270 + hc] + b_hh[270 + hc];

    {   // stage h1 tile: 64 rows x 12 granules
        int r = lane;
        int m = m0 + r;
        #pragma unroll
        for (int i = 0; i < 2; ++i) {
            int g = wv + 6 * i;   // 0..11
            uint4 v = {0u, 0u, 0u, 0u};
            if (m < M) v = *(const uint4*)(h1 + m * 96 + g * 8);
            *(uint4*)(&As[r][g * 8]) = v;
        }
    }
    __syncthreads();

    const int rbase = (lane >> 4) * 4;
    #pragma unroll
    for (int rs = 0; rs < 4; ++rs) {
        f32x4 accI = {0.f, 0.f, 0.f, 0.f};
        f32x4 accG = {0.f, 0.f, 0.f, 0.f};
        f32x4 accO = {0.f, 0.f, 0.f, 0.f};
        #pragma unroll
        for (int kk = 0; kk < 3; ++kk) {
            bf16x8 a = *(const bf16x8*)(&As[rs * 16 + r15][kk * 32 + k8 * 8]);
            accI = __builtin_amdgcn_mfma_f32_16x16x32_bf16(a, wf[0][kk], accI, 0, 0, 0);
            accG = __builtin_amdgcn_mfma_f32_16x16x32_bf16(a, wf[1][kk], accG, 0, 0, 0);
            accO = __builtin_amdgcn_mfma_f32_16x16x32_bf16(a, wf[2][kk], accO, 0, 0, 0);
        }
        if (h < 90) {
            #pragma unroll
            for (int rg = 0; rg < 4; ++rg) {
                int m = m0 + rs * 16 + rbase + rg;
                float iv = accI[rg] + bI;
                float gv = accG[rg] + bG;
                float ov = accO[rg] + bO;
                float c  = sigm(iv) * tanh_(gv);
                float o2 = sigm(ov) * tanh_(c);   // no outer sigmoid
                if (m < M) {
                    int b = m / 240;
                    int t = m - b * 240;
                    h2[b * 21600 + t * 90 + h] = f2bf(o2);
                }
            }
        }
    }
}

// ---------------------------------------------------------------------------
// Output head: per-b block; wave wv owns softmax group wv (10 logits).
// ---------------------------------------------------------------------------
__global__ __launch_bounds__(256) void k_out(
    const short* __restrict__ h2, const short* __restrict__ woutB,
    const float* __restrict__ outb, float* __restrict__ out)
{
    __shared__ short hs[21600];
    const int tid = threadIdx.x;
    const int b   = blockIdx.x;

    {   // stage h2 row (2700 x 16B)
        const uint4* src = (const uint4*)(h2 + b * 21600);
        #pragma unroll
        for (int i = 0; i < 11; ++i) {
            int idx = tid + 256 * i;
            if (idx < 2700) *(uint4*)(&hs[idx * 8]) = src[idx];
        }
    }
    __syncthreads();

    const int wv = tid >> 6, lane = tid & 63;
    float acc[10];
    #pragma unroll
    for (int j = 0; j < 10; ++j) acc[j] = 0.f;
    const short* wbase = woutB + (wv * 10) * 21600;

    for (int it = 0; it < 169; ++it) {
        int k = it * 128 + lane * 2;
        if (k < 21600) {
            unsigned int hu = *(const unsigned int*)(&hs[k]);
            float e0 = bf2f((short)(hu & 0xffff));
            float e1 = bf2f((short)(hu >> 16));
            #pragma unroll
            for (int j = 0; j < 10; ++j) {
                unsigned int wu = *(const unsigned int*)(wbase + j * 21600 + k);
                acc[j] += e0 * bf2f((short)(wu & 0xffff)) + e1 * bf2f((short)(wu >> 16));
            }
        }
    }
    #pragma unroll
    for (int j = 0; j < 10; ++j) {
        float v = acc[j];
        #pragma unroll
        for (int s = 1; s < 64; s <<= 1) v += __shfl_xor(v, s, 64);
        acc[j] = v;
    }
    if (lane == 0) {
        float vals[10]; float mx = -1e30f;
        #pragma unroll
        for (int j = 0; j < 10; ++j) {
            vals[j] = acc[j] + outb[wv * 10 + j];
            mx = fmaxf(mx, vals[j]);
        }
        float s = 0.f;
        #pragma unroll
        for (int j = 0; j < 10; ++j) { vals[j] = __expf(vals[j] - mx); s += vals[j]; }
        float inv = 1.f / s;
        #pragma unroll
        for (int j = 0; j < 10; ++j) out[b * 40 + wv * 10 + j] = vals[j] * inv;
    }
}

// ---------------------------------------------------------------------------
extern "C" void kernel_launch(void* const* d_in, const int* in_sizes, int n_in,
                              void* d_out, int out_size, void* d_ws, size_t ws_size,
                              hipStream_t stream)
{
    const float* x     = (const float*)d_in[0];
    const float* encW  = (const float*)d_in[1];
    const float* eb_ih = (const float*)d_in[2];
    const float* eb_hh = (const float*)d_in[3];
    const float* decW  = (const float*)d_in[4];
    const float* db_ih = (const float*)d_in[5];
    const float* db_hh = (const float*)d_in[6];
    const float* outW  = (const float*)d_in[7];
    const float* outb  = (const float*)d_in[8];
    float* out = (float*)d_out;

    const int B = in_sizes[0] / (3 * 60 * TT);
    const int M = B * TT;

    char* ws = (char*)d_ws;
    short* woutB = (short*)ws;                                    // 1,728,000 B
    short* wencP = (short*)(ws + 1728000);                        // 110,592 B
    short* wdecP = (short*)(ws + 1728000 + 110592);               //  55,296 B
    short* h1    = (short*)(ws + 1728000 + 110592 + 55296);       // M*96*2 B
    short* h2    = (short*)(ws + 1728000 + 110592 + 55296 + (size_t)M * 192);

    k_prep<<<dim3(3699), dim3(256), 0, stream>>>(outW, encW, decW, woutB, wencP, wdecP);
    const int nblk = (M + 63) / 64;
    k_enc<<<dim3(nblk), dim3(384), 0, stream>>>(x, wencP, eb_ih, eb_hh, h1, M);
    k_dec<<<dim3(nblk), dim3(384), 0, stream>>>(h1, wdecP, db_ih, db_hh, h2, M);
    k_out<<<dim3(B), dim3(256), 0, stream>>>(h2, woutB, outb, out);
}

// Round 2
// 499.708 us; speedup vs baseline: 1.2017x; 1.2017x over previous
//
#include <hip/hip_runtime.h>
#include <hip/hip_bf16.h>

// Sizes fixed by the problem
#define TT 240
#define FEAT 180
#define HID 90

typedef __attribute__((ext_vector_type(8))) short bf16x8;
typedef __attribute__((ext_vector_type(4))) float f32x4;

static __device__ __forceinline__ short f2bf(float f) {
    union { float f; unsigned int u; } c; c.f = f;
    return (short)((c.u + 0x8000u) >> 16);     // round-to-nearest (ties up); inputs finite
}
static __device__ __forceinline__ float fexp2(float x) { return __builtin_amdgcn_exp2f(x); }
static __device__ __forceinline__ float frcp(float x)  { return __builtin_amdgcn_rcpf(x); }
#define LOG2E 1.4426950408889634f
static __device__ __forceinline__ float sigm(float x)  { return frcp(1.f + fexp2(-LOG2E * x)); }
static __device__ __forceinline__ float tanh_(float x) { return 2.f * frcp(1.f + fexp2(-2.f * LOG2E * x)) - 1.f; }

// ---------------------------------------------------------------------------
// Weight repack (bf16):
//  woutB: [48][21600]  rows 40..47 zero
//  wencP: [288][192]   rows = gate*96+h (gates i,g,o; f dropped), zero-padded
//  wdecP: [288][96]
// ---------------------------------------------------------------------------
__global__ __launch_bounds__(256) void k_prep(
    const float* __restrict__ outW, const float* __restrict__ encW,
    const float* __restrict__ decW,
    short* __restrict__ woutB, short* __restrict__ wencP, short* __restrict__ wdecP)
{
    int idx = blockIdx.x * 256 + threadIdx.x;
    if (idx < 48 * 21600) {
        int row = idx / 21600, k = idx - row * 21600;
        woutB[idx] = (row < 40) ? f2bf(outW[row * 21600 + k]) : 0;
        return;
    }
    idx -= 48 * 21600;
    if (idx < 288 * 192) {
        int row = idx / 192, k = idx - row * 192;
        int gi = row / 96, h = row - gi * 96;
        float v = 0.f;
        if (h < 90 && k < 180) {
            int srow = (gi == 0 ? 0 : (gi == 1 ? 180 : 270)) + h;
            v = encW[srow * 180 + k];
        }
        wencP[idx] = f2bf(v);
        return;
    }
    idx -= 288 * 192;
    if (idx < 288 * 96) {
        int row = idx / 96, k = idx - row * 96;
        int gi = row / 96, h = row - gi * 96;
        float v = 0.f;
        if (h < 90 && k < 90) {
            int srow = (gi == 0 ? 0 : (gi == 1 ? 180 : 270)) + h;
            v = decW[srow * 90 + k];
        }
        wdecP[idx] = f2bf(v);
    }
}

// ---------------------------------------------------------------------------
// Fused encoder+decoder. Per block: 64 rows (m = b*240+t), 6 waves; wave wv
// owns h-tile [wv*16, wv*16+16) with W fragments in registers. h1 never
// leaves LDS. h2 assembled in LDS, then coalesced uint global write.
// h2 layout: [b][t*90+h] (= packed [B][21600] K-contiguous for the out GEMM).
// ---------------------------------------------------------------------------
__global__ __launch_bounds__(384) void k_ed(
    const float* __restrict__ x,
    const short* __restrict__ wencP, const short* __restrict__ wdecP,
    const float* __restrict__ eb_ih, const float* __restrict__ eb_hh,
    const float* __restrict__ db_ih, const float* __restrict__ db_hh,
    short* __restrict__ h2, int M)
{
    __shared__ short As[64][200];   // enc A tile (64x192 used); reused for h2 staging
    __shared__ short Hs[64][104];   // h1 tile (64x96 used)
    const int tid  = threadIdx.x;
    const int lane = tid & 63;
    const int wv   = tid >> 6;
    const int m0   = blockIdx.x * 64;
    const int r15  = lane & 15;
    const int k8   = lane >> 4;
    const int rbase = k8 * 4;

    // Encoder W fragments: 3 gates x 6 k-steps in VGPRs
    bf16x8 wfE[3][6];
    #pragma unroll
    for (int g = 0; g < 3; ++g) {
        const short* wp = wencP + (g * 96 + wv * 16 + r15) * 192 + k8 * 8;
        #pragma unroll
        for (int kk = 0; kk < 6; ++kk) wfE[g][kk] = *(const bf16x8*)(wp + kk * 32);
    }
    const int h  = wv * 16 + r15;
    const int hc = (h < 90) ? h : 89;
    const float bIe = eb_ih[hc] + eb_hh[hc];
    const float bGe = eb_ih[180 + hc] + eb_hh[180 + hc];
    const float bOe = eb_ih[270 + hc] + eb_hh[270 + hc];
    const float bId = db_ih[hc] + db_hh[hc];
    const float bGd = db_ih[180 + hc] + db_hh[180 + hc];
    const float bOd = db_ih[270 + hc] + db_hh[270 + hc];

    // Stage x tile: row r holds xe[m0+r][k] (fused transpose, coalesced over t)
    {
        const int r = lane;
        const int m = m0 + r;
        const bool mv = (m < M);
        const int b = m / 240;
        const int t = m - b * 240;
        const float* xb = x + b * 43200 + t;
        #pragma unroll
        for (int i = 0; i < 4; ++i) {
            int g = wv + 6 * i;               // granule 0..23 (8 bf16)
            short tmp[8];
            #pragma unroll
            for (int j = 0; j < 8; ++j) {
                int kk2 = g * 8 + j;
                float v = (mv && kk2 < 180) ? xb[kk2 * 240] : 0.f;
                tmp[j] = f2bf(v);
            }
            *(uint4*)(&As[r][g * 8]) = *(const uint4*)tmp;
        }
    }
    __syncthreads();

    // ---- Encoder: h1 -> LDS ----
    #pragma unroll
    for (int rs = 0; rs < 4; ++rs) {
        f32x4 aI = {0.f,0.f,0.f,0.f}, aG = {0.f,0.f,0.f,0.f}, aO = {0.f,0.f,0.f,0.f};
        #pragma unroll
        for (int kk = 0; kk < 6; ++kk) {
            bf16x8 a = *(const bf16x8*)(&As[rs * 16 + r15][kk * 32 + k8 * 8]);
            aI = __builtin_amdgcn_mfma_f32_16x16x32_bf16(a, wfE[0][kk], aI, 0, 0, 0);
            aG = __builtin_amdgcn_mfma_f32_16x16x32_bf16(a, wfE[1][kk], aG, 0, 0, 0);
            aO = __builtin_amdgcn_mfma_f32_16x16x32_bf16(a, wfE[2][kk], aO, 0, 0, 0);
        }
        #pragma unroll
        for (int rg = 0; rg < 4; ++rg) {
            float c  = sigm(aI[rg] + bIe) * tanh_(aG[rg] + bGe);
            float hv = sigm(aO[rg] + bOe) * tanh_(c);
            Hs[rs * 16 + rbase + rg][h] = f2bf(sigm(hv));   // extra sigmoid on enc out
        }
    }
    __syncthreads();

    // Decoder W fragments (enc fragments dead now)
    bf16x8 wfD[3][3];
    #pragma unroll
    for (int g = 0; g < 3; ++g) {
        const short* wp = wdecP + (g * 96 + wv * 16 + r15) * 96 + k8 * 8;
        #pragma unroll
        for (int kk = 0; kk < 3; ++kk) wfD[g][kk] = *(const bf16x8*)(wp + kk * 32);
    }

    // ---- Decoder: h2 -> LDS (reuse As, stride 96) ----
    short* h2s = &As[0][0];
    #pragma unroll
    for (int rs = 0; rs < 4; ++rs) {
        f32x4 aI = {0.f,0.f,0.f,0.f}, aG = {0.f,0.f,0.f,0.f}, aO = {0.f,0.f,0.f,0.f};
        #pragma unroll
        for (int kk = 0; kk < 3; ++kk) {
            bf16x8 a = *(const bf16x8*)(&Hs[rs * 16 + r15][kk * 32 + k8 * 8]);
            aI = __builtin_amdgcn_mfma_f32_16x16x32_bf16(a, wfD[0][kk], aI, 0, 0, 0);
            aG = __builtin_amdgcn_mfma_f32_16x16x32_bf16(a, wfD[1][kk], aG, 0, 0, 0);
            aO = __builtin_amdgcn_mfma_f32_16x16x32_bf16(a, wfD[2][kk], aO, 0, 0, 0);
        }
        #pragma unroll
        for (int rg = 0; rg < 4; ++rg) {
            float c  = sigm(aI[rg] + bId) * tanh_(aG[rg] + bGd);
            float o2 = sigm(aO[rg] + bOd) * tanh_(c);
            h2s[(rs * 16 + rbase + rg) * 96 + h] = f2bf(o2);
        }
    }
    __syncthreads();

    // Coalesced h2 write: 64 rows x 90 cols = 2880 uints
    #pragma unroll
    for (int i = 0; i < 8; ++i) {
        int idx = tid + 384 * i;
        if (idx < 2880) {
            int r  = idx / 45;
            int c2 = (idx - r * 45) * 2;
            int m  = m0 + r;
            if (m < M) {
                int b = m / 240, t = m - b * 240;
                *(unsigned int*)(h2 + b * 21600 + t * 90 + c2) =
                    *(const unsigned int*)(&h2s[r * 96 + c2]);
            }
        }
    }
}

// ---------------------------------------------------------------------------
// Output head GEMM: logits[b][n] = sum_k h2[b][k] * woutB[n][k]
// M=B rows, N=48 (40 valid), K=21600. K split 45 ways (15 K-steps each).
// A and B fragments stream directly from global (k-contiguous dwordx4).
// Partials -> ws, reduced in k_soft.  Requires B % 64 == 0.
// ---------------------------------------------------------------------------
#define KSPLIT 45
#define KCH    15      // K-steps (x32) per chunk: 45*15*32 = 21600
__global__ __launch_bounds__(256) void k_out(
    const short* __restrict__ h2, const short* __restrict__ woutB,
    float* __restrict__ part, int B)
{
    const int MT  = B >> 6;
    const int bid = blockIdx.x;
    const int kc  = bid / MT;
    const int mt  = bid - kc * MT;
    const int w    = threadIdx.x >> 6;
    const int lane = threadIdx.x & 63;
    const int r15  = lane & 15;
    const int k8   = lane >> 4;

    const int row = mt * 64 + w * 16 + r15;
    const short* aB = h2    + (size_t)row * 21600 + kc * (KCH * 32) + k8 * 8;
    const short* bB = woutB + (size_t)r15 * 21600 + kc * (KCH * 32) + k8 * 8;

    f32x4 a0 = {0.f,0.f,0.f,0.f}, a1 = {0.f,0.f,0.f,0.f}, a2 = {0.f,0.f,0.f,0.f};
    #pragma unroll 5
    for (int ks = 0; ks < KCH; ++ks) {
        bf16x8 a  = *(const bf16x8*)(aB + ks * 32);
        bf16x8 q0 = *(const bf16x8*)(bB + ks * 32);
        bf16x8 q1 = *(const bf16x8*)(bB + 16 * 21600 + ks * 32);
        bf16x8 q2 = *(const bf16x8*)(bB + 32 * 21600 + ks * 32);
        a0 = __builtin_amdgcn_mfma_f32_16x16x32_bf16(a, q0, a0, 0, 0, 0);
        a1 = __builtin_amdgcn_mfma_f32_16x16x32_bf16(a, q1, a1, 0, 0, 0);
        a2 = __builtin_amdgcn_mfma_f32_16x16x32_bf16(a, q2, a2, 0, 0, 0);
    }
    float* pb = part + ((size_t)kc * B + mt * 64 + w * 16) * 48;
    const int rb = k8 * 4;
    #pragma unroll
    for (int rg = 0; rg < 4; ++rg) {
        int r = rb + rg;
        pb[r * 48 +      r15] = a0[rg];
        pb[r * 48 + 16 + r15] = a1[rg];
        pb[r * 48 + 32 + r15] = a2[rg];
    }
}

// ---------------------------------------------------------------------------
// Reduce partials + bias + grouped softmax (4 groups of 10).
// ---------------------------------------------------------------------------
__global__ __launch_bounds__(64) void k_soft(
    const float* __restrict__ part, const float* __restrict__ outb,
    float* __restrict__ out, int B)
{
    const int b = blockIdx.x, t = threadIdx.x;
    __shared__ float vals[40];
    if (t < 40) {
        float s = outb[t];
        for (int kc = 0; kc < KSPLIT; ++kc) s += part[((size_t)kc * B + b) * 48 + t];
        vals[t] = s;
    }
    __syncthreads();
    if (t < 4) {
        float mx = -1e30f;
        #pragma unroll
        for (int j = 0; j < 10; ++j) mx = fmaxf(mx, vals[t * 10 + j]);
        float e[10], s = 0.f;
        #pragma unroll
        for (int j = 0; j < 10; ++j) { e[j] = fexp2(LOG2E * (vals[t * 10 + j] - mx)); s += e[j]; }
        float inv = frcp(s);
        #pragma unroll
        for (int j = 0; j < 10; ++j) out[b * 40 + t * 10 + j] = e[j] * inv;
    }
}

// ---------------------------------------------------------------------------
extern "C" void kernel_launch(void* const* d_in, const int* in_sizes, int n_in,
                              void* d_out, int out_size, void* d_ws, size_t ws_size,
                              hipStream_t stream)
{
    const float* x     = (const float*)d_in[0];
    const float* encW  = (const float*)d_in[1];
    const float* eb_ih = (const float*)d_in[2];
    const float* eb_hh = (const float*)d_in[3];
    const float* decW  = (const float*)d_in[4];
    const float* db_ih = (const float*)d_in[5];
    const float* db_hh = (const float*)d_in[6];
    const float* outW  = (const float*)d_in[7];
    const float* outb  = (const float*)d_in[8];
    float* out = (float*)d_out;

    const int B = in_sizes[0] / (3 * 60 * TT);
    const int M = B * TT;

    char* ws = (char*)d_ws;
    short* woutB = (short*)ws;                       // 48*21600*2     = 2,073,600 B
    short* wencP = (short*)(ws + 2073600);           // 288*192*2     =   110,592 B
    short* wdecP = (short*)(ws + 2184192);           // 288*96*2      =    55,296 B
    short* h2    = (short*)(ws + 2239488);           // B*21600*2     = B*43,200 B
    float* part  = (float*)(ws + 2239488 + (size_t)B * 43200);  // 45*B*48*4 B

    k_prep<<<dim3(4374), dim3(256), 0, stream>>>(outW, encW, decW, woutB, wencP, wdecP);
    const int nblk = (M + 63) / 64;
    k_ed<<<dim3(nblk), dim3(384), 0, stream>>>(x, wencP, wdecP, eb_ih, eb_hh,
                                               db_ih, db_hh, h2, M);
    k_out<<<dim3(KSPLIT * (B >> 6)), dim3(256), 0, stream>>>(h2, woutB, part, B);
    k_soft<<<dim3(B), dim3(64), 0, stream>>>(part, outb, out, B);
}

// Round 3
// 378.979 us; speedup vs baseline: 1.5845x; 1.3186x over previous
//
#include <hip/hip_runtime.h>
#include <hip/hip_bf16.h>

// Sizes fixed by the problem
#define TT 240
#define FEAT 180
#define HID 90

typedef __attribute__((ext_vector_type(8))) short bf16x8;
typedef __attribute__((ext_vector_type(4))) short s16x4;
typedef __attribute__((ext_vector_type(4))) float f32x4;

static __device__ __forceinline__ short f2bf(float f) {
    union { float f; unsigned int u; } c; c.f = f;
    return (short)((c.u + 0x8000u) >> 16);     // round-to-nearest (ties up); inputs finite
}
static __device__ __forceinline__ float fexp2(float x) { return __builtin_amdgcn_exp2f(x); }
static __device__ __forceinline__ float frcp(float x)  { return __builtin_amdgcn_rcpf(x); }
#define LOG2E 1.4426950408889634f
static __device__ __forceinline__ float sigm(float x)  { return frcp(1.f + fexp2(-LOG2E * x)); }
static __device__ __forceinline__ float tanh_(float x) { return 2.f * frcp(1.f + fexp2(-2.f * LOG2E * x)) - 1.f; }
static __device__ __forceinline__ unsigned int pk2(float lo, float hi) {
    return (unsigned int)(unsigned short)f2bf(lo) | ((unsigned int)(unsigned short)f2bf(hi) << 16);
}

// ---------------------------------------------------------------------------
// Weight repack (bf16):
//  woutB: [48][21600]  rows 40..47 zero   (vectorized: 16B in / 16B out)
//  wencP: [288][192]   rows = gate*96+h (gates i,g,o; f dropped), zero-padded
//  wdecP: [288][96]
// ---------------------------------------------------------------------------
__global__ __launch_bounds__(256) void k_prep(
    const float* __restrict__ outW, const float* __restrict__ encW,
    const float* __restrict__ decW,
    short* __restrict__ woutB, short* __restrict__ wencP, short* __restrict__ wdecP)
{
    int idx = blockIdx.x * 256 + threadIdx.x;
    if (idx < 129600) {                       // 48*21600/8 granules of 8 shorts
        int row = idx / 2700, v = idx - row * 2700;
        uint4 w = {0u, 0u, 0u, 0u};
        if (row < 40) {
            const float* s = outW + row * 21600 + v * 8;
            f32x4 a = *(const f32x4*)(s);
            f32x4 b = *(const f32x4*)(s + 4);
            w.x = pk2(a[0], a[1]); w.y = pk2(a[2], a[3]);
            w.z = pk2(b[0], b[1]); w.w = pk2(b[2], b[3]);
        }
        *(uint4*)(woutB + row * 21600 + v * 8) = w;
        return;
    }
    idx -= 129600;
    if (idx < 288 * 192) {
        int row = idx / 192, k = idx - row * 192;
        int gi = row / 96, h = row - gi * 96;
        float v = 0.f;
        if (h < 90 && k < 180) {
            int srow = (gi == 0 ? 0 : (gi == 1 ? 180 : 270)) + h;
            v = encW[srow * 180 + k];
        }
        wencP[idx] = f2bf(v);
        return;
    }
    idx -= 288 * 192;
    if (idx < 288 * 96) {
        int row = idx / 96, k = idx - row * 96;
        int gi = row / 96, h = row - gi * 96;
        float v = 0.f;
        if (h < 90 && k < 90) {
            int srow = (gi == 0 ? 0 : (gi == 1 ? 180 : 270)) + h;
            v = decW[srow * 90 + k];
        }
        wdecP[idx] = f2bf(v);
    }
}

// ---------------------------------------------------------------------------
// Fused encoder+decoder. Block = (b, q): rows t = q*60 .. q*60+59 of batch b
// (rows 60..63 of the MFMA tile are zero-padded). 6 waves; wave wv owns
// h-tile [wv*16, wv*16+16) with W fragments in registers.
// Staging: coalesced float4 loads of x[b][f][t0..t0+59] + in-register 4x4
// transpose -> short4 LDS writes (8B-aligned, stride 200).
// h1 lives in LDS only. h2 written as one contiguous 5400-short stream.
// ---------------------------------------------------------------------------
__global__ __launch_bounds__(384) void k_ed(
    const float* __restrict__ x,
    const short* __restrict__ wencP, const short* __restrict__ wdecP,
    const float* __restrict__ eb_ih, const float* __restrict__ eb_hh,
    const float* __restrict__ db_ih, const float* __restrict__ db_hh,
    short* __restrict__ h2)
{
    __shared__ short As[64][200];   // enc A tile (64x192 used); reused for h2 staging
    __shared__ short Hs[64][104];   // h1 tile (64x96 used)
    const int tid  = threadIdx.x;
    const int lane = tid & 63;
    const int wv   = tid >> 6;
    const int b    = blockIdx.x >> 2;
    const int q    = blockIdx.x & 3;
    const int r15  = lane & 15;
    const int k8   = lane >> 4;
    const int rbase = k8 * 4;

    // Encoder W fragments: 3 gates x 6 k-steps in VGPRs
    bf16x8 wfE[3][6];
    #pragma unroll
    for (int g = 0; g < 3; ++g) {
        const short* wp = wencP + (g * 96 + wv * 16 + r15) * 192 + k8 * 8;
        #pragma unroll
        for (int kk = 0; kk < 6; ++kk) wfE[g][kk] = *(const bf16x8*)(wp + kk * 32);
    }
    const int h  = wv * 16 + r15;
    const int hc = (h < 90) ? h : 89;
    const float bIe = eb_ih[hc] + eb_hh[hc];
    const float bGe = eb_ih[180 + hc] + eb_hh[180 + hc];
    const float bOe = eb_ih[270 + hc] + eb_hh[270 + hc];
    const float bId = db_ih[hc] + db_hh[hc];
    const float bGd = db_ih[180 + hc] + db_hh[180 + hc];
    const float bOd = db_ih[270 + hc] + db_hh[270 + hc];

    // Zero pad regions: cols 180..191 (all rows), rows 60..63 (cols 0..179)
    {
        int row = tid / 6, u = tid - row * 6;                  // 384 = 64*6
        *(unsigned int*)(&As[row][180 + u * 2]) = 0u;
        if (tid < 360) {
            int r = 60 + tid / 90, c2 = (tid - (tid / 90) * 90) * 2;
            *(unsigned int*)(&As[r][c2]) = 0u;
        }
    }

    // Stage x: 675 tasks; task = (fb, v): load x[b][fb*4..fb*4+3][t0+v*4..+3]
    // as 4 coalesced float4s, 4x4 register transpose, 4 short4 LDS writes.
    {
        const float* xs = x + b * 43200 + q * 60;
        #pragma unroll
        for (int it = 0; it < 2; ++it) {
            int task = tid + 384 * it;
            if (task < 675) {
                int fb = task / 15, v = task - fb * 15;
                const float* p = xs + (fb * 4) * 240 + v * 4;
                f32x4 L0 = *(const f32x4*)(p);
                f32x4 L1 = *(const f32x4*)(p + 240);
                f32x4 L2 = *(const f32x4*)(p + 480);
                f32x4 L3 = *(const f32x4*)(p + 720);
                #pragma unroll
                for (int i = 0; i < 4; ++i) {
                    s16x4 w = { f2bf(L0[i]), f2bf(L1[i]), f2bf(L2[i]), f2bf(L3[i]) };
                    *(s16x4*)(&As[v * 4 + i][fb * 4]) = w;
                }
            }
        }
    }
    __syncthreads();

    // ---- Encoder: h1 -> LDS ----
    #pragma unroll
    for (int rs = 0; rs < 4; ++rs) {
        f32x4 aI = {0.f,0.f,0.f,0.f}, aG = {0.f,0.f,0.f,0.f}, aO = {0.f,0.f,0.f,0.f};
        #pragma unroll
        for (int kk = 0; kk < 6; ++kk) {
            bf16x8 a = *(const bf16x8*)(&As[rs * 16 + r15][kk * 32 + k8 * 8]);
            aI = __builtin_amdgcn_mfma_f32_16x16x32_bf16(a, wfE[0][kk], aI, 0, 0, 0);
            aG = __builtin_amdgcn_mfma_f32_16x16x32_bf16(a, wfE[1][kk], aG, 0, 0, 0);
            aO = __builtin_amdgcn_mfma_f32_16x16x32_bf16(a, wfE[2][kk], aO, 0, 0, 0);
        }
        #pragma unroll
        for (int rg = 0; rg < 4; ++rg) {
            float c  = sigm(aI[rg] + bIe) * tanh_(aG[rg] + bGe);
            float hv = sigm(aO[rg] + bOe) * tanh_(c);
            Hs[rs * 16 + rbase + rg][h] = f2bf(sigm(hv));   // extra sigmoid on enc out
        }
    }
    __syncthreads();

    // Decoder W fragments (enc fragments dead now)
    bf16x8 wfD[3][3];
    #pragma unroll
    for (int g = 0; g < 3; ++g) {
        const short* wp = wdecP + (g * 96 + wv * 16 + r15) * 96 + k8 * 8;
        #pragma unroll
        for (int kk = 0; kk < 3; ++kk) wfD[g][kk] = *(const bf16x8*)(wp + kk * 32);
    }

    // ---- Decoder: h2 -> LDS (reuse As, stride 96) ----
    short* h2s = &As[0][0];
    #pragma unroll
    for (int rs = 0; rs < 4; ++rs) {
        f32x4 aI = {0.f,0.f,0.f,0.f}, aG = {0.f,0.f,0.f,0.f}, aO = {0.f,0.f,0.f,0.f};
        #pragma unroll
        for (int kk = 0; kk < 3; ++kk) {
            bf16x8 a = *(const bf16x8*)(&Hs[rs * 16 + r15][kk * 32 + k8 * 8]);
            aI = __builtin_amdgcn_mfma_f32_16x16x32_bf16(a, wfD[0][kk], aI, 0, 0, 0);
            aG = __builtin_amdgcn_mfma_f32_16x16x32_bf16(a, wfD[1][kk], aG, 0, 0, 0);
            aO = __builtin_amdgcn_mfma_f32_16x16x32_bf16(a, wfD[2][kk], aO, 0, 0, 0);
        }
        #pragma unroll
        for (int rg = 0; rg < 4; ++rg) {
            float c  = sigm(aI[rg] + bId) * tanh_(aG[rg] + bGd);
            float o2 = sigm(aO[rg] + bOd) * tanh_(c);
            h2s[(rs * 16 + rbase + rg) * 96 + h] = f2bf(o2);
        }
    }
    __syncthreads();

    // Contiguous coalesced h2 write: 60 rows x 90 cols = 2700 uints
    unsigned int* hp = (unsigned int*)(h2 + (size_t)b * 21600 + q * 5400);
    #pragma unroll
    for (int i = 0; i < 8; ++i) {
        int idx = tid + 384 * i;
        if (idx < 2700) {
            int r = idx / 45, c = idx - r * 45;
            hp[idx] = *(const unsigned int*)(&h2s[r * 96 + c * 2]);
        }
    }
}

// ---------------------------------------------------------------------------
// Output head GEMM: logits[b][n] = sum_k h2[b][k] * woutB[n][k]
// M=B, N=48 (40 valid), K=21600 = 135 chunks x 160. One wave per
// (16-row M-tile, K-chunk): 135 * B/16 waves (~34/CU at B=1024).
// ---------------------------------------------------------------------------
#define KSPLIT 135
#define KCH    5       // K-steps (x32) per chunk: 135*5*32 = 21600
__global__ __launch_bounds__(64) void k_out(
    const short* __restrict__ h2, const short* __restrict__ woutB,
    float* __restrict__ part, int B)
{
    const int MT  = B >> 4;              // 16-row tiles
    const int bid = blockIdx.x;
    const int kc  = bid / MT;
    const int mt  = bid - kc * MT;
    const int lane = threadIdx.x & 63;
    const int r15  = lane & 15;
    const int k8   = lane >> 4;

    const int row = mt * 16 + r15;
    const short* aB = h2    + (size_t)row * 21600 + kc * (KCH * 32) + k8 * 8;
    const short* bB = woutB + (size_t)r15 * 21600 + kc * (KCH * 32) + k8 * 8;

    f32x4 a0 = {0.f,0.f,0.f,0.f}, a1 = {0.f,0.f,0.f,0.f}, a2 = {0.f,0.f,0.f,0.f};
    #pragma unroll
    for (int ks = 0; ks < KCH; ++ks) {
        bf16x8 a  = *(const bf16x8*)(aB + ks * 32);
        bf16x8 q0 = *(const bf16x8*)(bB + ks * 32);
        bf16x8 q1 = *(const bf16x8*)(bB + 16 * 21600 + ks * 32);
        bf16x8 q2 = *(const bf16x8*)(bB + 32 * 21600 + ks * 32);
        a0 = __builtin_amdgcn_mfma_f32_16x16x32_bf16(a, q0, a0, 0, 0, 0);
        a1 = __builtin_amdgcn_mfma_f32_16x16x32_bf16(a, q1, a1, 0, 0, 0);
        a2 = __builtin_amdgcn_mfma_f32_16x16x32_bf16(a, q2, a2, 0, 0, 0);
    }
    float* pb = part + ((size_t)kc * B + mt * 16) * 48;
    #pragma unroll
    for (int rg = 0; rg < 4; ++rg) {
        int r = k8 * 4 + rg;
        pb[r * 48 +      r15] = a0[rg];
        pb[r * 48 + 16 + r15] = a1[rg];
        pb[r * 48 + 32 + r15] = a2[rg];
    }
}

// ---------------------------------------------------------------------------
// Reduce partials (6-way parallel over kc) + bias + grouped softmax (4x10).
// ---------------------------------------------------------------------------
__global__ __launch_bounds__(256) void k_soft(
    const float* __restrict__ part, const float* __restrict__ outb,
    float* __restrict__ out, int B)
{
    const int b = blockIdx.x, tid = threadIdx.x;
    __shared__ float psum[240];
    __shared__ float vals[40];
    if (tid < 240) {
        int o = tid % 40, g = tid / 40;
        float s = 0.f;
        for (int kc = g; kc < KSPLIT; kc += 6)
            s += part[((size_t)kc * B + b) * 48 + o];
        psum[tid] = s;
    }
    __syncthreads();
    if (tid < 40) {
        float s = outb[tid];
        #pragma unroll
        for (int g = 0; g < 6; ++g) s += psum[tid + 40 * g];
        vals[tid] = s;
    }
    __syncthreads();
    if (tid < 4) {
        float mx = -1e30f;
        #pragma unroll
        for (int j = 0; j < 10; ++j) mx = fmaxf(mx, vals[tid * 10 + j]);
        float e[10], s = 0.f;
        #pragma unroll
        for (int j = 0; j < 10; ++j) { e[j] = fexp2(LOG2E * (vals[tid * 10 + j] - mx)); s += e[j]; }
        float inv = frcp(s);
        #pragma unroll
        for (int j = 0; j < 10; ++j) out[b * 40 + tid * 10 + j] = e[j] * inv;
    }
}

// ---------------------------------------------------------------------------
extern "C" void kernel_launch(void* const* d_in, const int* in_sizes, int n_in,
                              void* d_out, int out_size, void* d_ws, size_t ws_size,
                              hipStream_t stream)
{
    const float* x     = (const float*)d_in[0];
    const float* encW  = (const float*)d_in[1];
    const float* eb_ih = (const float*)d_in[2];
    const float* eb_hh = (const float*)d_in[3];
    const float* decW  = (const float*)d_in[4];
    const float* db_ih = (const float*)d_in[5];
    const float* db_hh = (const float*)d_in[6];
    const float* outW  = (const float*)d_in[7];
    const float* outb  = (const float*)d_in[8];
    float* out = (float*)d_out;

    const int B = in_sizes[0] / (3 * 60 * TT);

    char* ws = (char*)d_ws;
    short* woutB = (short*)ws;                       // 48*21600*2 = 2,073,600 B
    short* wencP = (short*)(ws + 2073600);           // 288*192*2  =   110,592 B
    short* wdecP = (short*)(ws + 2184192);           // 288*96*2   =    55,296 B
    short* h2    = (short*)(ws + 2239488);           // B*21600*2  = B*43,200 B
    float* part  = (float*)(ws + 2239488 + (size_t)B * 43200);  // 135*B*48*4 B

    k_prep<<<dim3(831), dim3(256), 0, stream>>>(outW, encW, decW, woutB, wencP, wdecP);
    k_ed<<<dim3(B * 4), dim3(384), 0, stream>>>(x, wencP, wdecP, eb_ih, eb_hh,
                                                db_ih, db_hh, h2);
    k_out<<<dim3(KSPLIT * (B >> 4)), dim3(64), 0, stream>>>(h2, woutB, part, B);
    k_soft<<<dim3(B), dim3(256), 0, stream>>>(part, outb, out, B);
}

// Round 4
// 361.074 us; speedup vs baseline: 1.6631x; 1.0496x over previous
//
#include <hip/hip_runtime.h>
#include <hip/hip_bf16.h>

// Sizes fixed by the problem
#define TT 240
#define FEAT 180
#define HID 90

typedef __attribute__((ext_vector_type(8))) short bf16x8;
typedef __attribute__((ext_vector_type(4))) short s16x4;
typedef __attribute__((ext_vector_type(4))) float f32x4;

static __device__ __forceinline__ short f2bf(float f) {
    union { float f; unsigned int u; } c; c.f = f;
    return (short)((c.u + 0x8000u) >> 16);     // round-to-nearest (ties up); inputs finite
}
static __device__ __forceinline__ float fexp2(float x) { return __builtin_amdgcn_exp2f(x); }
static __device__ __forceinline__ float frcp(float x)  { return __builtin_amdgcn_rcpf(x); }
#define LOG2E 1.4426950408889634f
static __device__ __forceinline__ float sigm(float x)  { return frcp(1.f + fexp2(-LOG2E * x)); }
static __device__ __forceinline__ float tanh_(float x) { return 2.f * frcp(1.f + fexp2(-2.f * LOG2E * x)) - 1.f; }
static __device__ __forceinline__ unsigned int pk2(float lo, float hi) {
    return (unsigned int)(unsigned short)f2bf(lo) | ((unsigned int)(unsigned short)f2bf(hi) << 16);
}

// ---------------------------------------------------------------------------
// Weight repack (bf16):
//  woutB: [48][21600]  rows 40..47 zero   (vectorized: 16B in / 16B out)
//  wencP: [288][192]   rows = gate*96+h (gates i,g,o; f dropped), zero-padded
//  wdecP: [288][96]
// ---------------------------------------------------------------------------
__global__ __launch_bounds__(256) void k_prep(
    const float* __restrict__ outW, const float* __restrict__ encW,
    const float* __restrict__ decW,
    short* __restrict__ woutB, short* __restrict__ wencP, short* __restrict__ wdecP)
{
    int idx = blockIdx.x * 256 + threadIdx.x;
    if (idx < 129600) {                       // 48*21600/8 granules of 8 shorts
        int row = idx / 2700, v = idx - row * 2700;
        uint4 w = {0u, 0u, 0u, 0u};
        if (row < 40) {
            const float* s = outW + row * 21600 + v * 8;
            f32x4 a = *(const f32x4*)(s);
            f32x4 b = *(const f32x4*)(s + 4);
            w.x = pk2(a[0], a[1]); w.y = pk2(a[2], a[3]);
            w.z = pk2(b[0], b[1]); w.w = pk2(b[2], b[3]);
        }
        *(uint4*)(woutB + row * 21600 + v * 8) = w;
        return;
    }
    idx -= 129600;
    if (idx < 288 * 192) {
        int row = idx / 192, k = idx - row * 192;
        int gi = row / 96, h = row - gi * 96;
        float v = 0.f;
        if (h < 90 && k < 180) {
            int srow = (gi == 0 ? 0 : (gi == 1 ? 180 : 270)) + h;
            v = encW[srow * 180 + k];
        }
        wencP[idx] = f2bf(v);
        return;
    }
    idx -= 288 * 192;
    if (idx < 288 * 96) {
        int row = idx / 96, k = idx - row * 96;
        int gi = row / 96, h = row - gi * 96;
        float v = 0.f;
        if (h < 90 && k < 90) {
            int srow = (gi == 0 ? 0 : (gi == 1 ? 180 : 270)) + h;
            v = decW[srow * 90 + k];
        }
        wdecP[idx] = f2bf(v);
    }
}

// ---------------------------------------------------------------------------
// Fused encoder+decoder. Block = (b, q): rows t = q*60..q*60+59 of batch b.
// Single 25.6 KB LDS buffer (As) -> 5 blocks/CU (30 waves, vs 9 before).
// Phase flow: stage x -> enc MFMA (h1 in regs) -> sync -> h1 into As cols
// 0..95 -> sync -> dec MFMA -> sync -> h2 into As (packed 96) -> sync ->
// coalesced global write. h1/h2 pad rows/cols are benign (W zero-cols).
// ---------------------------------------------------------------------------
__global__ __launch_bounds__(384) void k_ed(
    const float* __restrict__ x,
    const short* __restrict__ wencP, const short* __restrict__ wdecP,
    const float* __restrict__ eb_ih, const float* __restrict__ eb_hh,
    const float* __restrict__ db_ih, const float* __restrict__ db_hh,
    short* __restrict__ h2)
{
    __shared__ short As[64][200];   // x tile (cols 0..191); later h1 (cols 0..95); later h2 packed
    const int tid  = threadIdx.x;
    const int lane = tid & 63;
    const int wv   = tid >> 6;
    const int b    = blockIdx.x >> 2;
    const int q    = blockIdx.x & 3;
    const int r15  = lane & 15;
    const int k8   = lane >> 4;
    const int rbase = k8 * 4;

    // Encoder W fragments: 3 gates x 6 k-steps in VGPRs
    bf16x8 wfE[3][6];
    #pragma unroll
    for (int g = 0; g < 3; ++g) {
        const short* wp = wencP + (g * 96 + wv * 16 + r15) * 192 + k8 * 8;
        #pragma unroll
        for (int kk = 0; kk < 6; ++kk) wfE[g][kk] = *(const bf16x8*)(wp + kk * 32);
    }
    const int h  = wv * 16 + r15;
    const int hc = (h < 90) ? h : 89;
    const float bIe = eb_ih[hc] + eb_hh[hc];
    const float bGe = eb_ih[180 + hc] + eb_hh[180 + hc];
    const float bOe = eb_ih[270 + hc] + eb_hh[270 + hc];
    const float bId = db_ih[hc] + db_hh[hc];
    const float bGd = db_ih[180 + hc] + db_hh[180 + hc];
    const float bOd = db_ih[270 + hc] + db_hh[270 + hc];

    // Zero pad regions: cols 180..191 (all rows), rows 60..63 (cols 0..179)
    {
        int row = tid / 6, u = tid - row * 6;                  // 384 = 64*6
        *(unsigned int*)(&As[row][180 + u * 2]) = 0u;
        if (tid < 360) {
            int r = 60 + tid / 90, c2 = (tid - (tid / 90) * 90) * 2;
            *(unsigned int*)(&As[r][c2]) = 0u;
        }
    }

    // Stage x: 675 tasks; task = (fb, v): load x[b][fb*4..fb*4+3][t0+v*4..+3]
    // as 4 coalesced float4s, 4x4 register transpose, 4 short4 LDS writes.
    {
        const float* xs = x + b * 43200 + q * 60;
        #pragma unroll
        for (int it = 0; it < 2; ++it) {
            int task = tid + 384 * it;
            if (task < 675) {
                int fb = task / 15, v = task - fb * 15;
                const float* p = xs + (fb * 4) * 240 + v * 4;
                f32x4 L0 = *(const f32x4*)(p);
                f32x4 L1 = *(const f32x4*)(p + 240);
                f32x4 L2 = *(const f32x4*)(p + 480);
                f32x4 L3 = *(const f32x4*)(p + 720);
                #pragma unroll
                for (int i = 0; i < 4; ++i) {
                    s16x4 w = { f2bf(L0[i]), f2bf(L1[i]), f2bf(L2[i]), f2bf(L3[i]) };
                    *(s16x4*)(&As[v * 4 + i][fb * 4]) = w;
                }
            }
        }
    }
    __syncthreads();

    // ---- Encoder: h1 -> registers (16 bf16 per lane) ----
    short h1v[16];
    #pragma unroll
    for (int rs = 0; rs < 4; ++rs) {
        f32x4 aI = {0.f,0.f,0.f,0.f}, aG = {0.f,0.f,0.f,0.f}, aO = {0.f,0.f,0.f,0.f};
        #pragma unroll
        for (int kk = 0; kk < 6; ++kk) {
            bf16x8 a = *(const bf16x8*)(&As[rs * 16 + r15][kk * 32 + k8 * 8]);
            aI = __builtin_amdgcn_mfma_f32_16x16x32_bf16(a, wfE[0][kk], aI, 0, 0, 0);
            aG = __builtin_amdgcn_mfma_f32_16x16x32_bf16(a, wfE[1][kk], aG, 0, 0, 0);
            aO = __builtin_amdgcn_mfma_f32_16x16x32_bf16(a, wfE[2][kk], aO, 0, 0, 0);
        }
        #pragma unroll
        for (int rg = 0; rg < 4; ++rg) {
            float c  = sigm(aI[rg] + bIe) * tanh_(aG[rg] + bGe);
            float hv = sigm(aO[rg] + bOe) * tanh_(c);
            h1v[rs * 4 + rg] = f2bf(sigm(hv));   // extra sigmoid on enc out
        }
    }
    __syncthreads();          // all waves done reading x from As

    // h1 -> As cols 0..95 (stride 200)
    #pragma unroll
    for (int j = 0; j < 16; ++j)
        As[(j >> 2) * 16 + rbase + (j & 3)][h] = h1v[j];

    // Decoder W fragments (global loads overlap the barrier)
    bf16x8 wfD[3][3];
    #pragma unroll
    for (int g = 0; g < 3; ++g) {
        const short* wp = wdecP + (g * 96 + wv * 16 + r15) * 96 + k8 * 8;
        #pragma unroll
        for (int kk = 0; kk < 3; ++kk) wfD[g][kk] = *(const bf16x8*)(wp + kk * 32);
    }
    __syncthreads();

    // ---- Decoder: h2 -> registers ----
    short h2v[16];
    #pragma unroll
    for (int rs = 0; rs < 4; ++rs) {
        f32x4 aI = {0.f,0.f,0.f,0.f}, aG = {0.f,0.f,0.f,0.f}, aO = {0.f,0.f,0.f,0.f};
        #pragma unroll
        for (int kk = 0; kk < 3; ++kk) {
            bf16x8 a = *(const bf16x8*)(&As[rs * 16 + r15][kk * 32 + k8 * 8]);
            aI = __builtin_amdgcn_mfma_f32_16x16x32_bf16(a, wfD[0][kk], aI, 0, 0, 0);
            aG = __builtin_amdgcn_mfma_f32_16x16x32_bf16(a, wfD[1][kk], aG, 0, 0, 0);
            aO = __builtin_amdgcn_mfma_f32_16x16x32_bf16(a, wfD[2][kk], aO, 0, 0, 0);
        }
        #pragma unroll
        for (int rg = 0; rg < 4; ++rg) {
            float c  = sigm(aI[rg] + bId) * tanh_(aG[rg] + bGd);
            float o2 = sigm(aO[rg] + bOd) * tanh_(c);
            h2v[rs * 4 + rg] = f2bf(o2);
        }
    }
    __syncthreads();          // all waves done reading h1 from As

    // h2 -> As packed stride 96 (rows 0..63, col h can be 90..95: within row slot)
    short* h2s = &As[0][0];
    #pragma unroll
    for (int j = 0; j < 16; ++j)
        h2s[((j >> 2) * 16 + rbase + (j & 3)) * 96 + h] = h2v[j];
    __syncthreads();

    // Contiguous coalesced h2 write: 60 rows x 90 cols = 2700 uints
    unsigned int* hp = (unsigned int*)(h2 + (size_t)b * 21600 + q * 5400);
    #pragma unroll
    for (int i = 0; i < 8; ++i) {
        int idx = tid + 384 * i;
        if (idx < 2700) {
            int r = idx / 45, c = idx - r * 45;
            hp[idx] = *(const unsigned int*)(&h2s[r * 96 + c * 2]);
        }
    }
}

// ---------------------------------------------------------------------------
// Output head GEMM: logits[b][n] = sum_k h2[b][k] * woutB[n][k]
// M=B, N=48 (40 valid), K=21600 = 45 chunks x 480. Block = 256 thr (4 waves),
// 64-row M-tile, B-chunk staged in LDS (48x480, stride 488 -> 2-way-free).
// A fragments stream from global (k-contiguous dwordx4).
// ---------------------------------------------------------------------------
#define KSPLIT 45
#define KST    15      // K-steps (x32) per chunk: 45*15*32 = 21600
__global__ __launch_bounds__(256) void k_out(
    const short* __restrict__ h2, const short* __restrict__ woutB,
    float* __restrict__ part, int B)
{
    __shared__ short Bs[48][488];
    const int MT  = B >> 6;              // 64-row tiles
    const int bid = blockIdx.x;
    const int kc  = bid / MT;
    const int mt  = bid - kc * MT;
    const int tid = threadIdx.x;

    {   // stage B chunk: 48 rows x 480 shorts = 2880 uint4 granules
        const int k0 = kc * 480;
        #pragma unroll
        for (int j = 0; j < 12; ++j) {
            int g = tid + 256 * j;
            if (g < 2880) {
                int r = g / 60, c = g - r * 60;
                *(uint4*)(&Bs[r][c * 8]) =
                    *(const uint4*)(woutB + (size_t)r * 21600 + k0 + c * 8);
            }
        }
    }
    __syncthreads();

    const int w = tid >> 6, lane = tid & 63;
    const int r15 = lane & 15, k8 = lane >> 4;
    const int row = mt * 64 + w * 16 + r15;
    const short* aB = h2 + (size_t)row * 21600 + kc * 480 + k8 * 8;

    f32x4 a0 = {0.f,0.f,0.f,0.f}, a1 = {0.f,0.f,0.f,0.f}, a2 = {0.f,0.f,0.f,0.f};
    #pragma unroll 5
    for (int ks = 0; ks < KST; ++ks) {
        bf16x8 a  = *(const bf16x8*)(aB + ks * 32);
        bf16x8 q0 = *(const bf16x8*)(&Bs[r15][ks * 32 + k8 * 8]);
        bf16x8 q1 = *(const bf16x8*)(&Bs[16 + r15][ks * 32 + k8 * 8]);
        bf16x8 q2 = *(const bf16x8*)(&Bs[32 + r15][ks * 32 + k8 * 8]);
        a0 = __builtin_amdgcn_mfma_f32_16x16x32_bf16(a, q0, a0, 0, 0, 0);
        a1 = __builtin_amdgcn_mfma_f32_16x16x32_bf16(a, q1, a1, 0, 0, 0);
        a2 = __builtin_amdgcn_mfma_f32_16x16x32_bf16(a, q2, a2, 0, 0, 0);
    }
    float* pb = part + ((size_t)kc * B + mt * 64 + w * 16) * 48;
    #pragma unroll
    for (int rg = 0; rg < 4; ++rg) {
        int r = k8 * 4 + rg;
        pb[r * 48 +      r15] = a0[rg];
        pb[r * 48 + 16 + r15] = a1[rg];
        pb[r * 48 + 32 + r15] = a2[rg];
    }
}

// ---------------------------------------------------------------------------
// Reduce partials (6-way parallel over kc) + bias + grouped softmax (4x10).
// ---------------------------------------------------------------------------
__global__ __launch_bounds__(256) void k_soft(
    const float* __restrict__ part, const float* __restrict__ outb,
    float* __restrict__ out, int B)
{
    const int b = blockIdx.x, tid = threadIdx.x;
    __shared__ float psum[240];
    __shared__ float vals[40];
    if (tid < 240) {
        int o = tid % 40, g = tid / 40;
        float s = 0.f;
        for (int kc = g; kc < KSPLIT; kc += 6)
            s += part[((size_t)kc * B + b) * 48 + o];
        psum[tid] = s;
    }
    __syncthreads();
    if (tid < 40) {
        float s = outb[tid];
        #pragma unroll
        for (int g = 0; g < 6; ++g) s += psum[tid + 40 * g];
        vals[tid] = s;
    }
    __syncthreads();
    if (tid < 4) {
        float mx = -1e30f;
        #pragma unroll
        for (int j = 0; j < 10; ++j) mx = fmaxf(mx, vals[tid * 10 + j]);
        float e[10], s = 0.f;
        #pragma unroll
        for (int j = 0; j < 10; ++j) { e[j] = fexp2(LOG2E * (vals[tid * 10 + j] - mx)); s += e[j]; }
        float inv = frcp(s);
        #pragma unroll
        for (int j = 0; j < 10; ++j) out[b * 40 + tid * 10 + j] = e[j] * inv;
    }
}

// ---------------------------------------------------------------------------
extern "C" void kernel_launch(void* const* d_in, const int* in_sizes, int n_in,
                              void* d_out, int out_size, void* d_ws, size_t ws_size,
                              hipStream_t stream)
{
    const float* x     = (const float*)d_in[0];
    const float* encW  = (const float*)d_in[1];
    const float* eb_ih = (const float*)d_in[2];
    const float* eb_hh = (const float*)d_in[3];
    const float* decW  = (const float*)d_in[4];
    const float* db_ih = (const float*)d_in[5];
    const float* db_hh = (const float*)d_in[6];
    const float* outW  = (const float*)d_in[7];
    const float* outb  = (const float*)d_in[8];
    float* out = (float*)d_out;

    const int B = in_sizes[0] / (3 * 60 * TT);

    char* ws = (char*)d_ws;
    short* woutB = (short*)ws;                       // 48*21600*2 = 2,073,600 B
    short* wencP = (short*)(ws + 2073600);           // 288*192*2  =   110,592 B
    short* wdecP = (short*)(ws + 2184192);           // 288*96*2   =    55,296 B
    short* h2    = (short*)(ws + 2239488);           // B*21600*2  = B*43,200 B
    float* part  = (float*)(ws + 2239488 + (size_t)B * 43200);  // 45*B*48*4 B

    k_prep<<<dim3(831), dim3(256), 0, stream>>>(outW, encW, decW, woutB, wencP, wdecP);
    k_ed<<<dim3(B * 4), dim3(384), 0, stream>>>(x, wencP, wdecP, eb_ih, eb_hh,
                                                db_ih, db_hh, h2);
    k_out<<<dim3(KSPLIT * (B >> 6)), dim3(256), 0, stream>>>(h2, woutB, part, B);
    k_soft<<<dim3(B), dim3(256), 0, stream>>>(part, outb, out, B);
}